// Round 1
// baseline (228.283 us; speedup 1.0000x reference)
//
#include <hip/hip_runtime.h>

// Problem: quantized SiLU, S=8192 rows x H=4096 cols, per-row scales.
//   x_f  = x * sx[row]
//   y_q  = clip(rint(sigmoid(x_f)/sy[row]), -127, 127)
//   y_f  = y_q * sy[row]
//   out  = clip(rint(x_f*y_f/so[row]), -127, 127)
// Output buffer is float32: [S*H] out values, then [S] scale_out copy.

#define SEQ_LEN 8192
#define HIDDEN  4096
#define QMAX_F  127.0f

// 4096 elems/row -> 1024 int4 vectors per row (pow2: row = vid >> 10)
#define VECS_PER_ROW_SHIFT 10
#define TOTAL_VECS ((SEQ_LEN * (long long)HIDDEN) / 4)   // 8,388,608

__device__ __forceinline__ float silu_q_one(int xi, float s_x, float s_y,
                                            float rcp_none, float s_o) {
    (void)rcp_none;
    float xf  = (float)xi * s_x;                 // dequant (exact f32 mul, matches np)
    float e   = expf(-xf);                       // ~1 ulp; only divergence source vs np
    float sig = 1.0f / (1.0f + e);               // IEEE div, correctly rounded
    float yq  = rintf(sig / s_y);                // IEEE div + round-half-even = np.round
    yq        = fminf(fmaxf(yq, -QMAX_F), QMAX_F);
    float yf  = yq * s_y;
    float of  = xf * yf;
    float oq  = rintf(of / s_o);
    return fminf(fmaxf(oq, -QMAX_F), QMAX_F);
}

__global__ __launch_bounds__(256) void silu_quant_kernel(
    const int*   __restrict__ x,
    const float* __restrict__ scale_x,
    const float* __restrict__ scale_y,
    const float* __restrict__ scale_out,
    float*       __restrict__ out)
{
    const int vid = blockIdx.x * blockDim.x + threadIdx.x;   // vec4 index, < 2^23
    if (vid >= (int)TOTAL_VECS) return;
    const int row = vid >> VECS_PER_ROW_SHIFT;

    const float s_x = scale_x[row];
    const float s_y = scale_y[row];
    const float s_o = scale_out[row];

    const int4 xv = ((const int4* __restrict__)x)[vid];

    float4 o;
    o.x = silu_q_one(xv.x, s_x, s_y, 0.f, s_o);
    o.y = silu_q_one(xv.y, s_x, s_y, 0.f, s_o);
    o.z = silu_q_one(xv.z, s_x, s_y, 0.f, s_o);
    o.w = silu_q_one(xv.w, s_x, s_y, 0.f, s_o);

    ((float4* __restrict__)out)[vid] = o;
}

extern "C" void kernel_launch(void* const* d_in, const int* in_sizes, int n_in,
                              void* d_out, int out_size, void* d_ws, size_t ws_size,
                              hipStream_t stream) {
    const int*   x         = (const int*)  d_in[0];
    const float* scale_x   = (const float*)d_in[1];
    const float* scale_y   = (const float*)d_in[2];
    const float* scale_out = (const float*)d_in[3];
    float*       out       = (float*)d_out;

    const int threads = 256;
    const int blocks  = (int)(TOTAL_VECS / threads);        // 32768, exact cover
    silu_quant_kernel<<<blocks, threads, 0, stream>>>(x, scale_x, scale_y, scale_out, out);

    // Second tuple output: copy scale_out verbatim after the matrix.
    hipMemcpyAsync(out + (size_t)SEQ_LEN * HIDDEN, scale_out,
                   SEQ_LEN * sizeof(float), hipMemcpyDeviceToDevice, stream);
}

// Round 3
// 226.200 us; speedup vs baseline: 1.0092x; 1.0092x over previous
//
#include <hip/hip_runtime.h>

// Quantized SiLU, S=8192 x H=4096, per-row scales.
//   x_f = x*sx[r]; y_q = clip(rint(sigmoid(x_f)/sy[r])); y_f = y_q*sy[r]
//   out = clip(rint(x_f*y_f/so[r]))
// Output float32 buffer: [S*H] values, then [S] scale_out copy.
//
// Layout: one block (256 thr) = one row (4096 elems = 1024 int4 vecs).
//   -> per-row scales are wave-uniform SGPR loads, amortized over 16 elems/thr.
// Numerics: y-path kept bit-identical to the R1-passing version (expf + two
// IEEE divs) — a y-flip in a row with s_y~s_o can cost ~|xf| (~6) quant steps.
// Final requant uses per-row reciprocal (flips there cost at most +-1).
// Nontemporal: x and out are each touched exactly once -> bypass cache alloc.
// NOTE: __builtin_nontemporal_* needs clang ext_vector types, not HIP_vector_type.

#define SEQ_LEN 8192
#define HIDDEN  4096
#define QMAX_F  127.0f
#define THREADS 256
#define VECS_PER_THREAD 4   // 256 thr * 4 vec * 4 elem = 4096 = one row

typedef int   iv4 __attribute__((ext_vector_type(4)));
typedef float fv4 __attribute__((ext_vector_type(4)));

__device__ __forceinline__ float silu_q_one(int xi, float s_x, float s_y,
                                            float r_o) {
    float xf  = (float)xi * s_x;                 // dequant (exact)
    float e   = expf(-xf);                       // ~1 ulp vs np.exp
    float sig = 1.0f / (1.0f + e);               // IEEE div (unchanged)
    float yq  = rintf(sig / s_y);                // IEEE div (unchanged)
    yq        = fminf(fmaxf(yq, -QMAX_F), QMAX_F);
    float yf  = yq * s_y;
    float of  = xf * yf;
    float oq  = rintf(of * r_o);                 // reciprocal-mul: flip cost <= 1
    return fminf(fmaxf(oq, -QMAX_F), QMAX_F);
}

__global__ __launch_bounds__(THREADS) void silu_quant_kernel(
    const int*   __restrict__ x,
    const float* __restrict__ scale_x,
    const float* __restrict__ scale_y,
    const float* __restrict__ scale_out,
    float*       __restrict__ out)
{
    const int row = blockIdx.x;                  // 8192 blocks, one per row

    // Wave-uniform scalar loads (same address for all lanes in the block).
    const float s_x = scale_x[row];
    const float s_y = scale_y[row];
    const float s_o = scale_out[row];
    const float r_o = 1.0f / s_o;

    const iv4* __restrict__ xrow = (const iv4*)(x + (size_t)row * HIDDEN);
    fv4*       __restrict__ orow = (fv4*)(out + (size_t)row * HIDDEN);

    #pragma unroll
    for (int k = 0; k < VECS_PER_THREAD; ++k) {
        const int v = threadIdx.x + k * THREADS; // coalesced within each pass
        iv4 xv = __builtin_nontemporal_load(xrow + v);
        fv4 o;
        o.x = silu_q_one(xv.x, s_x, s_y, r_o);
        o.y = silu_q_one(xv.y, s_x, s_y, r_o);
        o.z = silu_q_one(xv.z, s_x, s_y, r_o);
        o.w = silu_q_one(xv.w, s_x, s_y, r_o);
        __builtin_nontemporal_store(o, orow + v);
    }

    // Tuple output #2: scale_out appended after the matrix. One store per
    // block replaces the separate memcpy dispatch.
    if (threadIdx.x == 0)
        out[(size_t)SEQ_LEN * HIDDEN + row] = s_o;
}

extern "C" void kernel_launch(void* const* d_in, const int* in_sizes, int n_in,
                              void* d_out, int out_size, void* d_ws, size_t ws_size,
                              hipStream_t stream) {
    const int*   x         = (const int*)  d_in[0];
    const float* scale_x   = (const float*)d_in[1];
    const float* scale_y   = (const float*)d_in[2];
    const float* scale_out = (const float*)d_in[3];
    float*       out       = (float*)d_out;

    silu_quant_kernel<<<SEQ_LEN, THREADS, 0, stream>>>(
        x, scale_x, scale_y, scale_out, out);
}